// Round 14
// baseline (56.639 us; speedup 1.0000x reference)
//
#include <hip/hip_runtime.h>

#define NF       10000
#define PATCH    16
#define ENC      128
#define BB       8
#define HH       64
#define WW       32
#define NPOS     (BB*HH*WW)   // 16384
#define NBUCK    1792
#define CAP      32           // bucket capacity (lambda ~6.25; overflow handled)
#define OVFMAX   10240
#define QPB      32           // queries per K2 block (512 blocks)
#define FSUM_BLOCKS 40
#define XSUM_BLOCKS 64

// f32 sum of 16, shuffle-halving tree order (CONFIRMED ref order, R7-R13 PASS).
__device__ __forceinline__ float tree_sum16(const float* a) {
    float b0 = a[0] + a[8],  b1 = a[1] + a[9],  b2 = a[2] + a[10], b3 = a[3] + a[11];
    float b4 = a[4] + a[12], b5 = a[5] + a[13], b6 = a[6] + a[14], b7 = a[7] + a[15];
    float c0 = b0 + b4, c1 = b1 + b5, c2 = b2 + b6, c3 = b3 + b7;
    float d0 = c0 + c2, d1 = c1 + c3;
    return d0 + d1;
}

// ---------------------------------------------------------------------------
// K1: blocks [0,40): fs value per filter (bit-exact tree order) inserted
//     directly into fixed-capacity global buckets via atomicAdd (gcount was
//     zeroed by the preceding hipMemsetAsync). Overflow -> govf list.
//     blocks [40,104): xsum (bit-exact R7 math, VERBATIM R12).
// No serial phase anywhere; 104 blocks all parallel.
// ---------------------------------------------------------------------------
__global__ __launch_bounds__(256) void prep_kernel(const float* __restrict__ x,
                                                   const float* __restrict__ filters,
                                                   int* __restrict__ gcount,
                                                   float2* __restrict__ gbuck,
                                                   float2* __restrict__ govf,
                                                   float* __restrict__ xsum) {
    int bid = blockIdx.x;
    int tid = threadIdx.x;

    if (bid < FSUM_BLOCKS) {
        int n = bid * 256 + tid;
        if (n < NF) {
            const float4* fp = reinterpret_cast<const float4*>(filters + n * PATCH);
            float4 v0 = fp[0], v1 = fp[1], v2 = fp[2], v3 = fp[3];
            float a[16] = {v0.x, v0.y, v0.z, v0.w, v1.x, v1.y, v1.z, v1.w,
                           v2.x, v2.y, v2.z, v2.w, v3.x, v3.y, v3.z, v3.w};
            float val = tree_sum16(a);
            int k = (int)floorf(val * 100.0f + 0.5f);
            k = min(max(k, 0), NBUCK - 1);
            int p = atomicAdd(&gcount[k], 1);
            if (p < CAP) {
                gbuck[k * CAP + p] = make_float2(val, __int_as_float(n));
            } else {
                int q = atomicAdd(&gcount[NBUCK], 1);   // overflow list count
                if (q < OVFMAX) govf[q] = make_float2(val, __int_as_float(n));
            }
        }
        return;
    }

    __shared__ float lds[4][64][17];
    __shared__ float smn[4][16], sinv[4][16];
    int grp = (bid - FSUM_BLOCKS) * 4 + (tid >> 6);   // 0..255
    int h   = tid & 63;
    int g   = tid >> 6;
    int b   = grp >> 5, w = grp & 31;
    const float4* xp = reinterpret_cast<const float4*>(
        x + (size_t)(((b * HH + h) * WW + w) * PATCH));
    float4 v0 = xp[0], v1 = xp[1], v2 = xp[2], v3 = xp[3];
    float vv[16] = {v0.x, v0.y, v0.z, v0.w, v1.x, v1.y, v1.z, v1.w,
                    v2.x, v2.y, v2.z, v2.w, v3.x, v3.y, v3.z, v3.w};
    #pragma unroll
    for (int j = 0; j < 16; ++j) lds[g][h][j] = vv[j];
    __syncthreads();
    if (h < 16) {
        float mn = lds[g][0][h], mx = mn;
        for (int i = 1; i < 64; ++i) {
            float t = lds[g][i][h];
            mn = fminf(mn, t);
            mx = fmaxf(mx, t);
        }
        smn[g][h] = mn;
        float rg = (mx - mn) + 1e-8f;         // f32, reference order
        sinv[g][h] = 1.0f / rg;               // hoisted reciprocal (R7-confirmed)
    }
    __syncthreads();
    float xs[16];
    #pragma unroll
    for (int j = 0; j < 16; ++j) xs[j] = (vv[j] - smn[g][j]) * sinv[g][j];
    xsum[(b * HH + h) * WW + w] = tree_sum16(xs);
}

// ---------------------------------------------------------------------------
// K2: search + gather (structure VERBATIM R12 K3 — verified). Threads
// 0..QPB-1 ring-search from the global buckets (R9-verified prune + exact
// lexicographic (d,idx) comparator), then ALWAYS scan the overflow list
// (normally empty; superset-scan is exact). All 4 waves gather emb rows.
// Tiny LDS -> high occupancy -> gather/search latency hidden by TLP.
// ---------------------------------------------------------------------------
__global__ __launch_bounds__(256) void search_gather_kernel(
        const int* __restrict__ gcount, const float2* __restrict__ gbuck,
        const float2* __restrict__ govf, const float* __restrict__ xsum,
        const float* __restrict__ emb, float* __restrict__ out) {
    __shared__ int sidx[QPB];
    int tid = threadIdx.x;
    int lane = tid & 63, wv = tid >> 6;

    if (tid < QPB) {
        int q = blockIdx.x * QPB + tid;
        float s = xsum[q];
        int kq = (int)floorf(s * 100.0f + 0.5f);
        kq = min(max(kq, 0), NBUCK - 1);
        float bd = __builtin_inff();
        int bi = 0x7fffffff;
        for (int r = 0; r < NBUCK; ++r) {
            float bound = 0.01f * (float)r - 0.0052f;   // R9-verified prune
            if (bd < bound) break;
            #pragma unroll
            for (int side = 0; side < 2; ++side) {
                if (r == 0 && side == 1) continue;
                int k = side ? kq + r : kq - r;
                if ((unsigned)k >= NBUCK) continue;
                int cnt = min(gcount[k], CAP);
                const float2* row = gbuck + k * CAP;
                for (int p = 0; p < cnt; ++p) {
                    float2 m = row[p];
                    float d = fabsf(m.x - s);           // exact ref arithmetic
                    int mi = __float_as_int(m.y);
                    if (d < bd) { bd = d; bi = mi; }
                    else if (d == bd && mi < bi) { bi = mi; }
                }
            }
        }
        // overflow list: superset of remaining candidates; exact comparator
        int oc = min(gcount[NBUCK], OVFMAX);
        for (int p = 0; p < oc; ++p) {
            float2 m = govf[p];
            float d = fabsf(m.x - s);
            int mi = __float_as_int(m.y);
            if (d < bd) { bd = d; bi = mi; }
            else if (d == bd && mi < bi) { bi = mi; }
        }
        sidx[tid] = bi;
    }
    __syncthreads();

    #pragma unroll
    for (int i = 0; i < QPB / 4; ++i) {         // 8 rows per wave
        int row = i * 4 + wv;
        int bi  = sidx[row];
        int q   = blockIdx.x * QPB + row;
        const float2* er = reinterpret_cast<const float2*>(emb + (size_t)bi * ENC);
        float2*       op = reinterpret_cast<float2*>(out + (size_t)q * ENC);
        op[lane] = er[lane];
    }
}

// ---------------------------------------------------------------------------
extern "C" void kernel_launch(void* const* d_in, const int* in_sizes, int n_in,
                              void* d_out, int out_size, void* d_ws, size_t ws_size,
                              hipStream_t stream) {
    const float* x       = (const float*)d_in[0];  // (8,64,32,16)
    const float* filters = (const float*)d_in[1];  // (10000,16)
    const float* emb     = (const float*)d_in[2];  // (10000,128)
    float* out = (float*)d_out;                    // (8,64,32,128)

    // ws layout: gcount int[NBUCK+1] @0 (pad 8K) | govf float2[OVFMAX] @8K
    //            | gbuck float2[NBUCK*CAP] @90112 | xsum float[NPOS] @548864
    char* wsb = (char*)d_ws;
    int*    gcount = (int*)wsb;
    float2* govf   = (float2*)(wsb + 8192);
    float2* gbuck  = (float2*)(wsb + 8192 + 81920);
    float*  xsum   = (float*)(wsb + 8192 + 81920 + 458752);

    hipMemsetAsync(gcount, 0, sizeof(int) * (NBUCK + 1), stream);
    prep_kernel<<<FSUM_BLOCKS + XSUM_BLOCKS, 256, 0, stream>>>(
        x, filters, gcount, gbuck, govf, xsum);
    search_gather_kernel<<<NPOS / QPB, 256, 0, stream>>>(
        gcount, gbuck, govf, xsum, emb, out);
}

// Round 15
// 38.217 us; speedup vs baseline: 1.4820x; 1.4820x over previous
//
#include <hip/hip_runtime.h>

#define NF       10000
#define NF_PAD   10240
#define PATCH    16
#define ENC      128
#define BB       8
#define HH       64
#define WW       32
#define NPOS     (BB*HH*WW)   // 16384
#define QPB      16           // queries per block (quarter of a (b,w) group)
#define RNG4     640          // float4s per wave range (2560 cands)

// f32 sum of 16, shuffle-halving tree order (CONFIRMED ref order, R7-R14 PASS).
__device__ __forceinline__ float tree_sum16(const float* a) {
    float b0 = a[0] + a[8],  b1 = a[1] + a[9],  b2 = a[2] + a[10], b3 = a[3] + a[11];
    float b4 = a[4] + a[12], b5 = a[5] + a[13], b6 = a[6] + a[14], b7 = a[7] + a[15];
    float c0 = b0 + b4, c1 = b1 + b5, c2 = b2 + b6, c3 = b3 + b7;
    float d0 = c0 + c2, d1 = c1 + c3;
    return d0 + d1;
}

// ---------------------------------------------------------------------------
// K1: fs[n] = tree_sum16(filters[n,:]), +inf pad to NF_PAD. 40 blocks.
// (VERBATIM R12 fsum branch — verified.)
// ---------------------------------------------------------------------------
__global__ __launch_bounds__(256) void fs_kernel(const float* __restrict__ filters,
                                                 float* __restrict__ fs) {
    int n = blockIdx.x * 256 + threadIdx.x;
    float val = __builtin_inff();
    if (n < NF) {
        const float4* fp = reinterpret_cast<const float4*>(filters + n * PATCH);
        float4 v0 = fp[0], v1 = fp[1], v2 = fp[2], v3 = fp[3];
        float a[16] = {v0.x, v0.y, v0.z, v0.w, v1.x, v1.y, v1.z, v1.w,
                       v2.x, v2.y, v2.z, v2.w, v3.x, v3.y, v3.z, v3.w};
        val = tree_sum16(a);
    }
    fs[n] = val;
}

// ---------------------------------------------------------------------------
// K2: 1024 blocks x 256 thr. Block = (group g = bid>>2, quarter = bid&3)
//  A: block-local x_sum for group g (VERBATIM R11 bit-exact math).
//  B: stage fs -> LDS (coalesced float4, 10/thread).
//  C: wave wv scans contiguous quarter-range [wv*2560, +2560) for the block's
//     16 queries (R13-verified lastit + reverse-rescan => exact per-range
//     (min dist, first idx)); pack (dist_bits<<32|idx) per wave into LDS.
//  D: u64 min over 4 packed partials = exact lexicographic (d, idx) =
//     global first-occurrence argmin (ranges index-ordered).
//  E: fused gather: wave wv copies rows wv*4..wv*4+3 (float2 lanes).
// LDS ~= 46 KB -> 3 blocks/CU = 12 waves/CU (fixes R13's 1 wave/SIMD).
// ---------------------------------------------------------------------------
__global__ __launch_bounds__(256) void argmin_gather_kernel(
        const float* __restrict__ x, const float* __restrict__ fs,
        const float* __restrict__ emb, float* __restrict__ out) {
    __shared__ float fsld[NF_PAD];                 // 40960 B
    __shared__ float xld[64][17];                  // 4352 B
    __shared__ float smn[16], sinv[16];
    __shared__ float sxs[64];
    __shared__ unsigned long long spart[4][QPB];   // 512 B
    __shared__ int   sidx[QPB];

    int tid  = threadIdx.x;
    int lane = tid & 63, wv = tid >> 6;
    int bid = blockIdx.x;
    int g = bid >> 2, quarter = bid & 3;
    int b = g >> 5, w = g & 31;

    // ---- B (issue early): stage fs -> LDS, coalesced ----------------------
    const float4* fg = reinterpret_cast<const float4*>(fs);
    float4*       fl = reinterpret_cast<float4*>(fsld);
    #pragma unroll
    for (int i = 0; i < NF_PAD / 4 / 256; ++i)     // 10 iters
        fl[i * 256 + tid] = fg[i * 256 + tid];

    // ---- A1: load x rows (h = tid < 64) -----------------------------------
    float vv[16];
    if (tid < 64) {
        const float4* xp = reinterpret_cast<const float4*>(
            x + (size_t)(((b * HH + tid) * WW + w) * PATCH));
        float4 v0 = xp[0], v1 = xp[1], v2 = xp[2], v3 = xp[3];
        vv[0]=v0.x; vv[1]=v0.y; vv[2]=v0.z; vv[3]=v0.w;
        vv[4]=v1.x; vv[5]=v1.y; vv[6]=v1.z; vv[7]=v1.w;
        vv[8]=v2.x; vv[9]=v2.y; vv[10]=v2.z; vv[11]=v2.w;
        vv[12]=v3.x; vv[13]=v3.y; vv[14]=v3.z; vv[15]=v3.w;
        #pragma unroll
        for (int j = 0; j < 16; ++j) xld[tid][j] = vv[j];
    }
    __syncthreads();
    // ---- A2: min/max over h (bit-exact R7 sequential order) ---------------
    if (tid < 16) {
        float mn = xld[0][tid], mx = mn;
        for (int i = 1; i < 64; ++i) {
            float t = xld[i][tid];
            mn = fminf(mn, t);
            mx = fmaxf(mx, t);
        }
        smn[tid] = mn;
        float rg = (mx - mn) + 1e-8f;      // f32, reference order
        sinv[tid] = 1.0f / rg;             // hoisted reciprocal (R7-confirmed)
    }
    __syncthreads();
    // ---- A3: x_sum --------------------------------------------------------
    if (tid < 64) {
        float xs[16];
        #pragma unroll
        for (int j = 0; j < 16; ++j) xs[j] = (vv[j] - smn[j]) * sinv[j];
        sxs[tid] = tree_sum16(xs);
    }
    __syncthreads();

    // ---- C: per-wave quarter-range scan for 16 queries --------------------
    float s[QPB], m[QPB];
    int lastit[QPB];
    #pragma unroll
    for (int j = 0; j < QPB; ++j) {
        s[j] = sxs[quarter * QPB + j];
        m[j] = __builtin_inff();
        lastit[j] = 0;
    }
    const float4* f4p = reinterpret_cast<const float4*>(fsld) + wv * RNG4;
    #pragma unroll 2
    for (int it = 0; it < 10; ++it) {
        float4 c = f4p[it * 64 + lane];    // cands wv*2560 + it*256 + lane*4 +k
        #pragma unroll
        for (int j = 0; j < QPB; ++j) {
            float d0 = fabsf(c.x - s[j]);  // exact ref arithmetic
            float d1 = fabsf(c.y - s[j]);
            float d2 = fabsf(c.z - s[j]);
            float d3 = fabsf(c.w - s[j]);
            float d4 = fminf(fminf(d0, d1), fminf(d2, d3));
            if (d4 < m[j]) { m[j] = d4; lastit[j] = it; }   // strict improve
        }
    }
    #pragma unroll
    for (int j = 0; j < QPB; ++j) {
        float M = m[j];
        #pragma unroll
        for (int d = 1; d < 64; d <<= 1) M = fminf(M, __shfl_xor(M, d, 64));
        int li = 0x7fffffff;
        if (m[j] == M) {
            float4 c = f4p[lastit[j] * 64 + lane];
            int base = wv * 2560 + lastit[j] * 256 + lane * 4;
            if (fabsf(c.w - s[j]) == M) li = base + 3;   // reverse overwrite
            if (fabsf(c.z - s[j]) == M) li = base + 2;   //  -> keeps first
            if (fabsf(c.y - s[j]) == M) li = base + 1;
            if (fabsf(c.x - s[j]) == M) li = base + 0;
        }
        #pragma unroll
        for (int d = 1; d < 64; d <<= 1) li = min(li, __shfl_xor(li, d, 64));
        if (lane == 0)
            spart[wv][j] = ((unsigned long long)__float_as_uint(M) << 32) |
                           (unsigned int)li;
    }
    __syncthreads();

    // ---- D: exact lexicographic combine across the 4 ordered ranges -------
    if (tid < QPB) {
        unsigned long long p0 = spart[0][tid], p1 = spart[1][tid];
        unsigned long long p2 = spart[2][tid], p3 = spart[3][tid];
        unsigned long long bp = min(min(p0, p1), min(p2, p3));
        sidx[tid] = (int)(bp & 0xffffffffu);
    }
    __syncthreads();

    // ---- E: fused gather, 4 rows per wave, float2 lanes -------------------
    #pragma unroll
    for (int i = 0; i < 4; ++i) {
        int row = wv * 4 + i;              // 0..15
        int bi  = sidx[row];
        int h   = quarter * QPB + row;
        int pos = (b * HH + h) * WW + w;
        const float2* er = reinterpret_cast<const float2*>(emb + (size_t)bi * ENC);
        float2*       op = reinterpret_cast<float2*>(out + (size_t)pos * ENC);
        op[lane] = er[lane];
    }
}

// ---------------------------------------------------------------------------
extern "C" void kernel_launch(void* const* d_in, const int* in_sizes, int n_in,
                              void* d_out, int out_size, void* d_ws, size_t ws_size,
                              hipStream_t stream) {
    const float* x       = (const float*)d_in[0];  // (8,64,32,16)
    const float* filters = (const float*)d_in[1];  // (10000,16)
    const float* emb     = (const float*)d_in[2];  // (10000,128)
    float* out = (float*)d_out;                    // (8,64,32,128)
    float* fs  = (float*)d_ws;                     // NF_PAD floats (40 KB)

    fs_kernel<<<NF_PAD / 256, 256, 0, stream>>>(filters, fs);
    argmin_gather_kernel<<<(NPOS / QPB), 256, 0, stream>>>(x, fs, emb, out);
}

// Round 16
// 28.187 us; speedup vs baseline: 2.0094x; 1.3559x over previous
//
#include <hip/hip_runtime.h>

#define NF       10000
#define PATCH    16
#define ENC      128
#define BB       8
#define HH       64
#define WW       32
#define NPOS     (BB*HH*WW)   // 16384
#define NBUCK    1792
#define CAP      64           // bucket capacity (peak bin ~30-40; P(>64) ~ 0)
#define OVFMAX   10240
#define FSUM_BLOCKS 40
#define XSUM_BLOCKS 64

// f32 sum of 16, shuffle-halving tree order (CONFIRMED ref order, R7-R15 PASS).
__device__ __forceinline__ float tree_sum16(const float* a) {
    float b0 = a[0] + a[8],  b1 = a[1] + a[9],  b2 = a[2] + a[10], b3 = a[3] + a[11];
    float b4 = a[4] + a[12], b5 = a[5] + a[13], b6 = a[6] + a[14], b7 = a[7] + a[15];
    float c0 = b0 + b4, c1 = b1 + b5, c2 = b2 + b6, c3 = b3 + b7;
    float d0 = c0 + c2, d1 = c1 + c3;
    return d0 + d1;
}

// ---------------------------------------------------------------------------
// K1: VERBATIM R14 prep (verified) with CAP=64.
//  blocks [0,40): fs -> global fixed-capacity buckets via atomicAdd;
//  blocks [40,104): xsum (bit-exact R7 math).
// ---------------------------------------------------------------------------
__global__ __launch_bounds__(256) void prep_kernel(const float* __restrict__ x,
                                                   const float* __restrict__ filters,
                                                   int* __restrict__ gcount,
                                                   float2* __restrict__ gbuck,
                                                   float2* __restrict__ govf,
                                                   float* __restrict__ xsum) {
    int bid = blockIdx.x;
    int tid = threadIdx.x;

    if (bid < FSUM_BLOCKS) {
        int n = bid * 256 + tid;
        if (n < NF) {
            const float4* fp = reinterpret_cast<const float4*>(filters + n * PATCH);
            float4 v0 = fp[0], v1 = fp[1], v2 = fp[2], v3 = fp[3];
            float a[16] = {v0.x, v0.y, v0.z, v0.w, v1.x, v1.y, v1.z, v1.w,
                           v2.x, v2.y, v2.z, v2.w, v3.x, v3.y, v3.z, v3.w};
            float val = tree_sum16(a);
            int k = (int)floorf(val * 100.0f + 0.5f);
            k = min(max(k, 0), NBUCK - 1);
            int p = atomicAdd(&gcount[k], 1);
            if (p < CAP) {
                gbuck[k * CAP + p] = make_float2(val, __int_as_float(n));
            } else {
                int q = atomicAdd(&gcount[NBUCK], 1);
                if (q < OVFMAX) govf[q] = make_float2(val, __int_as_float(n));
            }
        }
        return;
    }

    __shared__ float lds[4][64][17];
    __shared__ float smn[4][16], sinv[4][16];
    int grp = (bid - FSUM_BLOCKS) * 4 + (tid >> 6);   // 0..255
    int h   = tid & 63;
    int g   = tid >> 6;
    int b   = grp >> 5, w = grp & 31;
    const float4* xp = reinterpret_cast<const float4*>(
        x + (size_t)(((b * HH + h) * WW + w) * PATCH));
    float4 v0 = xp[0], v1 = xp[1], v2 = xp[2], v3 = xp[3];
    float vv[16] = {v0.x, v0.y, v0.z, v0.w, v1.x, v1.y, v1.z, v1.w,
                    v2.x, v2.y, v2.z, v2.w, v3.x, v3.y, v3.z, v3.w};
    #pragma unroll
    for (int j = 0; j < 16; ++j) lds[g][h][j] = vv[j];
    __syncthreads();
    if (h < 16) {
        float mn = lds[g][0][h], mx = mn;
        for (int i = 1; i < 64; ++i) {
            float t = lds[g][i][h];
            mn = fminf(mn, t);
            mx = fmaxf(mx, t);
        }
        smn[g][h] = mn;
        float rg = (mx - mn) + 1e-8f;         // f32, reference order
        sinv[g][h] = 1.0f / rg;               // hoisted reciprocal (R7-confirmed)
    }
    __syncthreads();
    float xs[16];
    #pragma unroll
    for (int j = 0; j < 16; ++j) xs[j] = (vv[j] - smn[g][j]) * sinv[g][j];
    xsum[(b * HH + h) * WW + w] = tree_sum16(xs);
}

// ---------------------------------------------------------------------------
// K2: ONE WAVE PER QUERY. Lanes split each ring's bucket members (coalesced);
// per-lane partial best packed as (dist_bits<<32 | idx); u64 min == exact
// lexicographic (d, idx) comparator (R15-verified packing) -> atomic-order
// independent, first-occurrence exact. Prune = verbatim R9 bound, applied to
// the wave-reduced best. Overflow list scanned unconditionally (superset).
// Same wave then gathers its 512B emb row. LDS=0 -> high occupancy; all
// latency hidden by TLP (fixes R12/R14's 32-active-thread serial walk).
// ---------------------------------------------------------------------------
__global__ __launch_bounds__(256) void search_gather_kernel(
        const int* __restrict__ gcount, const float2* __restrict__ gbuck,
        const float2* __restrict__ govf, const float* __restrict__ xsum,
        const float* __restrict__ emb, float* __restrict__ out) {
    int lane = threadIdx.x & 63;
    int wv   = threadIdx.x >> 6;
    int q    = blockIdx.x * 4 + wv;          // 4096 blocks x 4 waves = 16384
    float s  = xsum[q];
    int kq = (int)floorf(s * 100.0f + 0.5f);
    kq = min(max(kq, 0), NBUCK - 1);

    unsigned long long pbest = 0xFFFFFFFFFFFFFFFFULL;

    for (int r = 0; r < NBUCK; ++r) {
        // wave-reduced current best distance for the prune
        unsigned long long wb = pbest;
        #pragma unroll
        for (int d = 1; d < 64; d <<= 1) wb = min(wb, __shfl_xor(wb, d, 64));
        float bd = __uint_as_float((unsigned)(wb >> 32));
        if (bd < 0.01f * (float)r - 0.0052f) break;      // R9-verified prune

        int kl = kq - r, kh = kq + r;
        int cA = ((unsigned)kl < NBUCK) ? min(gcount[kl], CAP) : 0;
        int cB = (r > 0 && (unsigned)kh < NBUCK) ? min(gcount[kh], CAP) : 0;
        const float2* rowA = gbuck + (size_t)kl * CAP;
        const float2* rowB = gbuck + (size_t)kh * CAP;
        int tot = cA + cB;
        for (int p = lane; p < tot; p += 64) {
            float2 m = (p < cA) ? rowA[p] : rowB[p - cA];
            float d = fabsf(m.x - s);                    // exact ref arithmetic
            unsigned long long pk =
                ((unsigned long long)__float_as_uint(d) << 32) |
                (unsigned int)__float_as_int(m.y);
            pbest = min(pbest, pk);
        }
    }

    // overflow list: superset scan, lane-parallel, exact comparator
    int oc = min(gcount[NBUCK], OVFMAX);
    for (int p = lane; p < oc; p += 64) {
        float2 m = govf[p];
        float d = fabsf(m.x - s);
        unsigned long long pk =
            ((unsigned long long)__float_as_uint(d) << 32) |
            (unsigned int)__float_as_int(m.y);
        pbest = min(pbest, pk);
    }

    #pragma unroll
    for (int d = 1; d < 64; d <<= 1) pbest = min(pbest, __shfl_xor(pbest, d, 64));
    int bi = (int)(pbest & 0xffffffffu);

    const float2* er = reinterpret_cast<const float2*>(emb + (size_t)bi * ENC);
    float2*       op = reinterpret_cast<float2*>(out + (size_t)q * ENC);
    op[lane] = er[lane];
}

// ---------------------------------------------------------------------------
extern "C" void kernel_launch(void* const* d_in, const int* in_sizes, int n_in,
                              void* d_out, int out_size, void* d_ws, size_t ws_size,
                              hipStream_t stream) {
    const float* x       = (const float*)d_in[0];  // (8,64,32,16)
    const float* filters = (const float*)d_in[1];  // (10000,16)
    const float* emb     = (const float*)d_in[2];  // (10000,128)
    float* out = (float*)d_out;                    // (8,64,32,128)

    // ws: gcount int[NBUCK+1] @0 (pad 8K) | govf float2[OVFMAX] @8K (80K)
    //     | gbuck float2[NBUCK*CAP] @90112 (917504) | xsum float[NPOS] @1007616
    char* wsb = (char*)d_ws;
    int*    gcount = (int*)wsb;
    float2* govf   = (float2*)(wsb + 8192);
    float2* gbuck  = (float2*)(wsb + 8192 + 81920);
    float*  xsum   = (float*)(wsb + 8192 + 81920 + 917504);

    hipMemsetAsync(gcount, 0, sizeof(int) * (NBUCK + 1), stream);
    prep_kernel<<<FSUM_BLOCKS + XSUM_BLOCKS, 256, 0, stream>>>(
        x, filters, gcount, gbuck, govf, xsum);
    search_gather_kernel<<<NPOS / 4, 256, 0, stream>>>(
        gcount, gbuck, govf, xsum, emb, out);
}